// Round 12
// baseline (47.555 us; speedup 1.0000x reference)
//
#include <hip/hip_runtime.h>
#include <hip/hip_bf16.h>
#include <cstdint>

#define LL 256   // L
#define NN 512   // N
#define DD 256   // D
#define HH 8
#define EPSF 1e-5f
#define WGS 264  // padded LDS row stride (bf16 elems) for Wg

typedef __attribute__((ext_vector_type(8))) __bf16 bf16x8;
typedef __attribute__((ext_vector_type(4))) float f32x4;

static __device__ __forceinline__ void lb_sync() {
    // barrier WITHOUT vmcnt drain: LDS-publish only; global loads stay in flight
    __builtin_amdgcn_sched_barrier(0);
    asm volatile("s_waitcnt lgkmcnt(0)" ::: "memory");
    __builtin_amdgcn_s_barrier();
    __builtin_amdgcn_sched_barrier(0);
}

static __device__ __forceinline__ void load_group(
    const float* __restrict__ msa, int l, int row0, int col, int kb, float4 (&buf)[16])
{
    const float* rp = msa + ((size_t)(row0 + col) * LL + l) * DD + (kb << 3);
    #pragma unroll
    for (int ks = 0; ks < 8; ++ks) {
        buf[2 * ks]     = *(const float4*)(rp + ks * 32);
        buf[2 * ks + 1] = *(const float4*)(rp + ks * 32 + 4);
    }
}

static __device__ __forceinline__ void compute_group(
    const float4 (&buf)[16], const bf16x8 (&bfr)[8], f32x4& hacc, f32x4& gacc)
{
    #pragma unroll
    for (int ks = 0; ks < 8; ++ks) {
        float4 u = buf[2 * ks], v = buf[2 * ks + 1];
        bf16x8 a;
        a[0] = (__bf16)u.x; a[1] = (__bf16)u.y; a[2] = (__bf16)u.z; a[3] = (__bf16)u.w;
        a[4] = (__bf16)v.x; a[5] = (__bf16)v.y; a[6] = (__bf16)v.z; a[7] = (__bf16)v.w;
        hacc = __builtin_amdgcn_mfma_f32_16x16x32_bf16(a, bfr[ks], hacc, 0, 0, 0);
        gacc = __builtin_amdgcn_mfma_f32_16x16x32_bf16(a, a,       gacc, 0, 0, 0);
    }
}

static __device__ __forceinline__ void store_group(
    int nloc0, int col, int kb, const f32x4& hacc, const f32x4& gacc,
    float* logits, float* sS, float* sQ)
{
    #pragma unroll
    for (int i = 0; i < 4; ++i) {
        int n = nloc0 + (kb << 2) + i;       // C/D: col=lane&15, row=kb*4+i
        if (col < HH)       logits[col * NN + n] = hacc[i];
        else if (col == HH) sS[n] = hacc[i];
    }
    if (kb == (col >> 2)) sQ[nloc0 + col] = gacc[col & 3];   // Gram diagonal
}

__global__ __launch_bounds__(1024, 4) void k_fused(
    const float* __restrict__ msa, const float* __restrict__ Wq,
    const float* __restrict__ bq, const float* __restrict__ Wk,
    const float* __restrict__ gamma, const float* __restrict__ beta,
    float* __restrict__ out)
{
    const int l = blockIdx.x;
    const int tid = threadIdx.x, wave = tid >> 6, lane = tid & 63;
    const int col = lane & 15, kb = lane >> 4;

    __shared__ __align__(16) float logits[HH * NN];  // 16 KB
    __shared__ __align__(16) float sS[NN];           // Σx̂
    __shared__ __align__(16) float sQ[NN];           // Σx̂²
    __shared__ __align__(16) __bf16 WgL[16 * WGS];   // 8.25 KB
    __shared__ __align__(16) float wkt[32 * 256];    // 32 KB Wk row-tile
    __shared__ float lnx[DD];
    __shared__ float qv[DD];
    __shared__ float red8[8];
    __shared__ float stats[16];
    __shared__ float Gs[HH];

    // ---- prefetch this wave's group-0 rows (n = wave*16 .. +15); overlaps phase 1 ----
    float4 A[16];
    load_group(msa, l, wave * 16, col, kb, A);

    // ---------- Phase 1: Wg = gamma ⊙ (q·Wk) in LDS (coalesced paths) ----------
    {
        // LN of target row
        float x0 = (tid < DD) ? msa[(size_t)l * DD + tid] : 0.f;
        float s = x0, ss = x0 * x0;
        #pragma unroll
        for (int m = 32; m >= 1; m >>= 1) { s += __shfl_xor(s, m); ss += __shfl_xor(ss, m); }
        if (tid < DD && lane == 0) { red8[wave * 2] = s; red8[wave * 2 + 1] = ss; }
        lb_sync();
        if (tid < DD) {
            float sm = red8[0] + red8[2] + red8[4] + red8[6];
            float sq = red8[1] + red8[3] + red8[5] + red8[7];
            float mean = sm * (1.f / DD);
            float var  = sq * (1.f / DD) - mean * mean;
            float rs   = rsqrtf(var + EPSF);
            lnx[tid] = (x0 - mean) * rs * gamma[tid] + beta[tid];
        }
        lb_sync();
        // Wq GEMV, wave-cooperative: wave w -> rows w*16..+15, coalesced 1KB row reads
        {
            f32x4 lx = *(const f32x4*)(lnx + lane * 4);
            #pragma unroll 4
            for (int rr = 0; rr < 16; ++rr) {
                const int r = wave * 16 + rr;
                float4 wv = *(const float4*)(Wq + (size_t)r * DD + lane * 4);
                float p = wv.x * lx[0] + wv.y * lx[1] + wv.z * lx[2] + wv.w * lx[3];
                #pragma unroll
                for (int m = 32; m >= 1; m >>= 1) p += __shfl_xor(p, m);
                if (lane == 0) qv[r] = (p + bq[r]) * 0.17677669529663687f;
            }
        }
        lb_sync();
        // Wk GEMV via staged row-tiles: 8 x { stage Wk rows ks*32..+31 coalesced -> masked MAD }
        const int c = tid & 255, hb = tid >> 8;        // thread's column, head-base
        const float gm = gamma[c];
        float wacc[2] = {0.f, 0.f};                    // for h = hb, hb+4
        #pragma unroll 1
        for (int ks = 0; ks < 8; ++ks) {
            {   // stage: thread -> row tid>>5 (0..31), cols (tid&31)*8..+7
                const int rr = tid >> 5, cg = (tid & 31) * 8;
                const float* src = Wk + ((size_t)(ks * 32 + rr)) * DD + cg;
                *(float4*)(wkt + rr * 256 + cg)     = *(const float4*)(src);
                *(float4*)(wkt + rr * 256 + cg + 4) = *(const float4*)(src + 4);
            }
            lb_sync();
            #pragma unroll
            for (int hi = 0; hi < 2; ++hi) {
                const int h = hb + hi * 4;
                if (h == ks) {
                    float a = 0.f;
                    const float* qh = qv + h * 32;
                    #pragma unroll 8
                    for (int d = 0; d < 32; ++d)
                        a += qh[d] * wkt[d * 256 + c];
                    wacc[hi] = a;
                }
            }
            lb_sync();
        }
        WgL[hb * WGS + c]       = (__bf16)(gm * wacc[0]);
        WgL[(hb + 4) * WGS + c] = (__bf16)(gm * wacc[1]);
        if (tid < DD) {
            WgL[8 * WGS + tid] = (__bf16)1.0f;     // ones column -> row sums
            #pragma unroll
            for (int h = 9; h < 16; ++h) WgL[h * WGS + tid] = (__bf16)0.0f;
        }
        lb_sync();
        if (wave < HH) {                           // G[h] = sum_c Wg[h][c]
            float gsum = 0.f;
            #pragma unroll
            for (int i = 0; i < 4; ++i) gsum += (float)WgL[wave * WGS + lane * 4 + i];
            #pragma unroll
            for (int m = 32; m >= 1; m >>= 1) gsum += __shfl_xor(gsum, m);
            if (lane == 0) Gs[wave] = gsum;
        }
        lb_sync();
    }

    // ---------- B fragments ----------
    bf16x8 bfr[8];
    #pragma unroll
    for (int ks = 0; ks < 8; ++ks)
        bfr[ks] = *(const bf16x8*)&WgL[col * WGS + ks * 32 + kb * 8];

    // ---------- Main: 16 waves × 2 groups of 16 rows (512 rows total) ----------
    const f32x4 z = {0.f, 0.f, 0.f, 0.f};
    {
        f32x4 ha = z, ga = z;
        compute_group(A, bfr, ha, ga);
        store_group(wave * 16, col, kb, ha, ga, logits, sS, sQ);
    }
    load_group(msa, l, 256 + wave * 16, col, kb, A);
    {
        f32x4 ha = z, ga = z;
        compute_group(A, bfr, ha, ga);
        store_group(256 + wave * 16, col, kb, ha, ga, logits, sS, sQ);
    }
    lb_sync();

    // ---------- softmax stats: waves 0-7 -> head h=wave over all 512 n ----------
    if (wave < HH) {
        const int h = wave;
        const float Gh = Gs[h];
        const float* lp = logits + h * NN;
        float4 ra = ((const float4*)lp)[lane * 2];
        float4 rb = ((const float4*)lp)[lane * 2 + 1];
        float4 sa = ((const float4*)sS)[lane * 2];
        float4 sb = ((const float4*)sS)[lane * 2 + 1];
        float4 qa = ((const float4*)sQ)[lane * 2];
        float4 qb = ((const float4*)sQ)[lane * 2 + 1];
        float raw[8] = {ra.x, ra.y, ra.z, ra.w, rb.x, rb.y, rb.z, rb.w};
        float sv[8]  = {sa.x, sa.y, sa.z, sa.w, sb.x, sb.y, sb.z, sb.w};
        float qv2[8] = {qa.x, qa.y, qa.z, qa.w, qb.x, qb.y, qb.z, qb.w};
        float adj[8];
        #pragma unroll
        for (int i = 0; i < 8; ++i) {
            float mean = sv[i] * (1.f / DD);
            float var  = qv2[i] * (1.f / DD) - mean * mean;
            float rs   = rsqrtf(var + EPSF);
            adj[i] = rs * (raw[i] - mean * Gh);
        }
        float mx = adj[0];
        #pragma unroll
        for (int i = 1; i < 8; ++i) mx = fmaxf(mx, adj[i]);
        #pragma unroll
        for (int m = 32; m >= 1; m >>= 1) mx = fmaxf(mx, __shfl_xor(mx, m));
        float sm = 0.f;
        #pragma unroll
        for (int i = 0; i < 8; ++i) sm += __expf(adj[i] - mx);
        #pragma unroll
        for (int m = 32; m >= 1; m >>= 1) sm += __shfl_xor(sm, m);
        if (lane == 0) { stats[wave] = mx; stats[8 + wave] = 1.f / sm; }
    }
    lb_sync();

    // ---------- epilogue: thread t<512 -> n=t, 8 heads, fp32 out ----------
    if (tid < NN) {
        const int n = tid;
        float s = sS[n], q2 = sQ[n];
        float mean = s * (1.f / DD);
        float var  = q2 * (1.f / DD) - mean * mean;
        float rs   = rsqrtf(var + EPSF);
        float o[8];
        #pragma unroll
        for (int h = 0; h < HH; ++h) {
            float adj = rs * (logits[h * NN + n] - mean * Gs[h]);
            o[h] = __expf(adj - stats[h]) * stats[8 + h];
        }
        float* op = out + (size_t)n * LL * HH + (size_t)l * HH;
        float4 p0 = {o[0], o[1], o[2], o[3]};
        float4 p1 = {o[4], o[5], o[6], o[7]};
        *(float4*)(op)     = p0;
        *(float4*)(op + 4) = p1;
    }
}

extern "C" void kernel_launch(void* const* d_in, const int* in_sizes, int n_in,
                              void* d_out, int out_size, void* d_ws, size_t ws_size,
                              hipStream_t stream) {
    (void)in_sizes; (void)n_in; (void)out_size; (void)d_ws; (void)ws_size;
    const float* msa   = (const float*)d_in[0];
    const float* Wq    = (const float*)d_in[1];
    const float* bq    = (const float*)d_in[2];
    const float* Wk    = (const float*)d_in[3];
    // d_in[4] = bk: per-(l,h) constant in logits -> cancelled by softmax over n.
    const float* gamma = (const float*)d_in[5];
    const float* beta  = (const float*)d_in[6];
    k_fused<<<dim3(LL), dim3(1024), 0, stream>>>(msa, Wq, bq, Wk, gamma, beta, (float*)d_out);
}

// Round 13
// 41.117 us; speedup vs baseline: 1.1566x; 1.1566x over previous
//
#include <hip/hip_runtime.h>
#include <hip/hip_bf16.h>
#include <cstdint>

#define LL 256   // L
#define NN 512   // N
#define DD 256   // D
#define HH 8
#define EPSF 1e-5f
#define WGS 264  // padded LDS row stride (bf16 elems) for Wg

typedef __attribute__((ext_vector_type(8))) __bf16 bf16x8;
typedef __attribute__((ext_vector_type(4))) float f32x4;

static __device__ __forceinline__ void lb_sync() {
    // barrier WITHOUT vmcnt drain: LDS-publish only; global loads/stages stay in flight
    __builtin_amdgcn_sched_barrier(0);
    asm volatile("s_waitcnt lgkmcnt(0)" ::: "memory");
    __builtin_amdgcn_s_barrier();
    __builtin_amdgcn_sched_barrier(0);
}

static __device__ __forceinline__ void load_group(
    const float* __restrict__ msa, int l, int row0, int col, int kb, float4 (&buf)[16])
{
    const float* rp = msa + ((size_t)(row0 + col) * LL + l) * DD + (kb << 3);
    #pragma unroll
    for (int ks = 0; ks < 8; ++ks) {
        buf[2 * ks]     = *(const float4*)(rp + ks * 32);
        buf[2 * ks + 1] = *(const float4*)(rp + ks * 32 + 4);
    }
}

static __device__ __forceinline__ void compute_group(
    const float4 (&buf)[16], const bf16x8 (&bfr)[8], f32x4& hacc, f32x4& gacc)
{
    #pragma unroll
    for (int ks = 0; ks < 8; ++ks) {
        float4 u = buf[2 * ks], v = buf[2 * ks + 1];
        bf16x8 a;
        a[0] = (__bf16)u.x; a[1] = (__bf16)u.y; a[2] = (__bf16)u.z; a[3] = (__bf16)u.w;
        a[4] = (__bf16)v.x; a[5] = (__bf16)v.y; a[6] = (__bf16)v.z; a[7] = (__bf16)v.w;
        hacc = __builtin_amdgcn_mfma_f32_16x16x32_bf16(a, bfr[ks], hacc, 0, 0, 0);
        gacc = __builtin_amdgcn_mfma_f32_16x16x32_bf16(a, a,       gacc, 0, 0, 0);
    }
}

static __device__ __forceinline__ void store_group(
    int nloc0, int col, int kb, const f32x4& hacc, const f32x4& gacc,
    float* logits, float* sS, float* sQ)
{
    #pragma unroll
    for (int i = 0; i < 4; ++i) {
        int n = nloc0 + (kb << 2) + i;       // C/D: col=lane&15, row=kb*4+i
        if (col < HH)       logits[col * NN + n] = hacc[i];
        else if (col == HH) sS[n] = hacc[i];
    }
    if (kb == (col >> 2)) sQ[nloc0 + col] = gacc[col & 3];   // Gram diagonal
}

__global__ __launch_bounds__(1024, 4) void k_fused(
    const float* __restrict__ msa, const float* __restrict__ Wq,
    const float* __restrict__ bq, const float* __restrict__ Wk,
    const float* __restrict__ gamma, const float* __restrict__ beta,
    float* __restrict__ out)
{
    const int l = blockIdx.x;
    const int tid = threadIdx.x, wave = tid >> 6, lane = tid & 63;
    const int col = lane & 15, kb = lane >> 4;

    __shared__ __align__(16) float tile[128 * 256];  // 128 KB: g1 rows of waves 0-7 (swizzled)
    __shared__ __align__(16) float logits[HH * NN];  // 16 KB
    __shared__ __align__(16) float sS[NN];           // Σx̂
    __shared__ __align__(16) float sQ[NN];           // Σx̂²
    __shared__ __align__(16) __bf16 WgL[16 * WGS];   // 8.25 KB
    __shared__ float lnx[DD];
    __shared__ float qv[DD];
    __shared__ float red8[8];
    __shared__ float stats[16];
    __shared__ float Gs[HH];

    // ---- t=0: waves 0-7 stage their OWN g1 rows via global_load_lds (zero VGPR) ----
    if (wave < 8) {
        #pragma unroll
        for (int r = 0; r < 16; ++r) {
            const int n = 256 + wave * 16 + r;
            // pre-swizzled SOURCE chunk, linear LDS dest (m104/m173 pattern)
            const char* g = (const char*)(msa + ((size_t)n * LL + l) * DD)
                            + (((lane * 16) ^ ((r & 7) << 4)));
            __builtin_amdgcn_global_load_lds(
                (const __attribute__((address_space(1))) void*)g,
                (__attribute__((address_space(3))) void*)
                    ((char*)(tile + (size_t)(wave * 16 + r) * 256) + lane * 16),
                16, 0, 0);
        }
    }
    __builtin_amdgcn_sched_barrier(0);

    // ---------- Phase 1 (R11 form): Wg = gamma ⊙ (q·Wk) in LDS ----------
    {
        float x0 = (tid < DD) ? msa[(size_t)l * DD + tid] : 0.f;
        float s = x0, ss = x0 * x0;
        #pragma unroll
        for (int m = 32; m >= 1; m >>= 1) { s += __shfl_xor(s, m); ss += __shfl_xor(ss, m); }
        if (tid < DD && lane == 0) { red8[wave * 2] = s; red8[wave * 2 + 1] = ss; }
        lb_sync();
        if (tid < DD) {
            float sm = red8[0] + red8[2] + red8[4] + red8[6];
            float sq = red8[1] + red8[3] + red8[5] + red8[7];
            float mean = sm * (1.f / DD);
            float var  = sq * (1.f / DD) - mean * mean;
            float rs   = rsqrtf(var + EPSF);
            lnx[tid] = (x0 - mean) * rs * gamma[tid] + beta[tid];
        }
        lb_sync();
        // Wq GEMV: 4-way row split over 1024 threads, LDS partials in qv via two passes
        {
            const int r = tid & 255, qtr = tid >> 8;
            const float4* wr = (const float4*)(Wq + (size_t)r * DD) + qtr * 16;
            const float* lx = lnx + qtr * 64;
            float acc = 0.f;
            #pragma unroll 4
            for (int j = 0; j < 16; ++j) {
                float4 w4 = wr[j];
                acc += lx[4*j] * w4.x + lx[4*j+1] * w4.y + lx[4*j+2] * w4.z + lx[4*j+3] * w4.w;
            }
            // reduce 4 partials per row via LDS (reuse logits region as scratch)
            float* qpart = logits;   // 4*264 floats scratch, dead before logits written
            qpart[qtr * 264 + r] = acc;
            lb_sync();
            if (tid < DD)
                qv[tid] = (qpart[0 * 264 + tid] + qpart[1 * 264 + tid]
                         + qpart[2 * 264 + tid] + qpart[3 * 264 + tid]
                         + bq[tid]) * 0.17677669529663687f;
        }
        lb_sync();
        // Wk GEMV: 2 heads per thread: c = tid&255, h ∈ {tid>>8, (tid>>8)+4}
        {
            const int c = tid & 255, hb = tid >> 8;
            const float gm = gamma[c];
            #pragma unroll
            for (int hi = 0; hi < 2; ++hi) {
                int h = hb + hi * 4;
                float a = 0.f;
                const float* wk = Wk + ((size_t)h * 32) * DD + c;
                #pragma unroll 8
                for (int d = 0; d < 32; ++d)
                    a += qv[h * 32 + d] * wk[(size_t)d * DD];
                WgL[h * WGS + c] = (__bf16)(gm * a);
            }
        }
        if (tid < DD) {
            WgL[8 * WGS + tid] = (__bf16)1.0f;     // ones column -> row sums
            #pragma unroll
            for (int h = 9; h < 16; ++h) WgL[h * WGS + tid] = (__bf16)0.0f;
        }
        lb_sync();
        if (wave < HH) {                           // G[h] = sum_c Wg[h][c]
            float gsum = 0.f;
            #pragma unroll
            for (int i = 0; i < 4; ++i) gsum += (float)WgL[wave * WGS + lane * 4 + i];
            #pragma unroll
            for (int m = 32; m >= 1; m >>= 1) gsum += __shfl_xor(gsum, m);
            if (lane == 0) Gs[wave] = gsum;
        }
        lb_sync();
    }

    // ---------- B fragments ----------
    bf16x8 bfr[8];
    #pragma unroll
    for (int ks = 0; ks < 8; ++ks)
        bfr[ks] = *(const bf16x8*)&WgL[col * WGS + ks * 32 + kb * 8];

    // ---------- g0: VGPR load + compute (rows wave*16..+15) ----------
    const f32x4 z = {0.f, 0.f, 0.f, 0.f};
    float4 A[16];
    load_group(msa, l, wave * 16, col, kb, A);
    {
        f32x4 ha = z, ga = z;
        compute_group(A, bfr, ha, ga);
        store_group(wave * 16, col, kb, ha, ga, logits, sS, sQ);
    }

    // ---------- g1: waves 0-7 from LDS tile; waves 8-15 exposed VGPR reload ----------
    if (wave < 8) {
        asm volatile("s_waitcnt vmcnt(0)" ::: "memory");   // own stages complete
        __builtin_amdgcn_sched_barrier(0);
        f32x4 ha = z, ga = z;
        const char* tb = (const char*)(tile + (size_t)(wave * 16 + col) * 256);
        const int swz = (col & 7) << 4;
        #pragma unroll
        for (int ks = 0; ks < 8; ++ks) {
            float4 u = *(const float4*)(tb + ((ks * 128 + kb * 32) ^ swz));
            float4 v = *(const float4*)(tb + ((ks * 128 + kb * 32 + 16) ^ swz));
            bf16x8 a;
            a[0] = (__bf16)u.x; a[1] = (__bf16)u.y; a[2] = (__bf16)u.z; a[3] = (__bf16)u.w;
            a[4] = (__bf16)v.x; a[5] = (__bf16)v.y; a[6] = (__bf16)v.z; a[7] = (__bf16)v.w;
            ha = __builtin_amdgcn_mfma_f32_16x16x32_bf16(a, bfr[ks], ha, 0, 0, 0);
            ga = __builtin_amdgcn_mfma_f32_16x16x32_bf16(a, a,       ga, 0, 0, 0);
        }
        store_group(256 + wave * 16, col, kb, ha, ga, logits, sS, sQ);
    } else {
        load_group(msa, l, 256 + wave * 16, col, kb, A);
        f32x4 ha = z, ga = z;
        compute_group(A, bfr, ha, ga);
        store_group(256 + wave * 16, col, kb, ha, ga, logits, sS, sQ);
    }
    lb_sync();

    // ---------- softmax stats: waves 0-7 -> head h=wave over all 512 n ----------
    if (wave < HH) {
        const int h = wave;
        const float Gh = Gs[h];
        const float* lp = logits + h * NN;
        float4 ra = ((const float4*)lp)[lane * 2];
        float4 rb = ((const float4*)lp)[lane * 2 + 1];
        float4 sa = ((const float4*)sS)[lane * 2];
        float4 sb = ((const float4*)sS)[lane * 2 + 1];
        float4 qa = ((const float4*)sQ)[lane * 2];
        float4 qb = ((const float4*)sQ)[lane * 2 + 1];
        float raw[8] = {ra.x, ra.y, ra.z, ra.w, rb.x, rb.y, rb.z, rb.w};
        float sv[8]  = {sa.x, sa.y, sa.z, sa.w, sb.x, sb.y, sb.z, sb.w};
        float qv2[8] = {qa.x, qa.y, qa.z, qa.w, qb.x, qb.y, qb.z, qb.w};
        float adj[8];
        #pragma unroll
        for (int i = 0; i < 8; ++i) {
            float mean = sv[i] * (1.f / DD);
            float var  = qv2[i] * (1.f / DD) - mean * mean;
            float rs   = rsqrtf(var + EPSF);
            adj[i] = rs * (raw[i] - mean * Gh);
        }
        float mx = adj[0];
        #pragma unroll
        for (int i = 1; i < 8; ++i) mx = fmaxf(mx, adj[i]);
        #pragma unroll
        for (int m = 32; m >= 1; m >>= 1) mx = fmaxf(mx, __shfl_xor(mx, m));
        float sm = 0.f;
        #pragma unroll
        for (int i = 0; i < 8; ++i) sm += __expf(adj[i] - mx);
        #pragma unroll
        for (int m = 32; m >= 1; m >>= 1) sm += __shfl_xor(sm, m);
        if (lane == 0) { stats[wave] = mx; stats[8 + wave] = 1.f / sm; }
    }
    lb_sync();

    // ---------- epilogue: thread t<512 -> n=t, 8 heads, fp32 out ----------
    if (tid < NN) {
        const int n = tid;
        float s = sS[n], q2 = sQ[n];
        float mean = s * (1.f / DD);
        float var  = q2 * (1.f / DD) - mean * mean;
        float rs   = rsqrtf(var + EPSF);
        float o[8];
        #pragma unroll
        for (int h = 0; h < HH; ++h) {
            float adj = rs * (logits[h * NN + n] - mean * Gs[h]);
            o[h] = __expf(adj - stats[h]) * stats[8 + h];
        }
        float* op = out + (size_t)n * LL * HH + (size_t)l * HH;
        float4 p0 = {o[0], o[1], o[2], o[3]};
        float4 p1 = {o[4], o[5], o[6], o[7]};
        *(float4*)(op)     = p0;
        *(float4*)(op + 4) = p1;
    }
}

extern "C" void kernel_launch(void* const* d_in, const int* in_sizes, int n_in,
                              void* d_out, int out_size, void* d_ws, size_t ws_size,
                              hipStream_t stream) {
    (void)in_sizes; (void)n_in; (void)out_size; (void)d_ws; (void)ws_size;
    const float* msa   = (const float*)d_in[0];
    const float* Wq    = (const float*)d_in[1];
    const float* bq    = (const float*)d_in[2];
    const float* Wk    = (const float*)d_in[3];
    // d_in[4] = bk: per-(l,h) constant in logits -> cancelled by softmax over n.
    const float* gamma = (const float*)d_in[5];
    const float* beta  = (const float*)d_in[6];
    k_fused<<<dim3(LL), dim3(1024), 0, stream>>>(msa, Wq, bq, Wk, gamma, beta, (float*)d_out);
}

// Round 14
// 41.087 us; speedup vs baseline: 1.1574x; 1.0007x over previous
//
#include <hip/hip_runtime.h>
#include <hip/hip_bf16.h>
#include <cstdint>

#define LL 256   // L
#define NN 512   // N
#define DD 256   // D
#define HH 8
#define EPSF 1e-5f
#define WGS 264  // padded LDS row stride (bf16 elems) for Wg

typedef __attribute__((ext_vector_type(8))) __bf16 bf16x8;
typedef __attribute__((ext_vector_type(4))) float f32x4;

static __device__ __forceinline__ void lb_sync() {
    // barrier WITHOUT vmcnt drain: LDS-publish only; global loads stay in flight
    __builtin_amdgcn_sched_barrier(0);
    asm volatile("s_waitcnt lgkmcnt(0)" ::: "memory");
    __builtin_amdgcn_s_barrier();
    __builtin_amdgcn_sched_barrier(0);
}

static __device__ __forceinline__ void load_group(
    const float* __restrict__ msa, int l, int row0, int col, int kb, float4 (&buf)[16])
{
    const float* rp = msa + ((size_t)(row0 + col) * LL + l) * DD + (kb << 3);
    #pragma unroll
    for (int ks = 0; ks < 8; ++ks) {
        buf[2 * ks]     = *(const float4*)(rp + ks * 32);
        buf[2 * ks + 1] = *(const float4*)(rp + ks * 32 + 4);
    }
}

static __device__ __forceinline__ void compute_group(
    const float4 (&buf)[16], const bf16x8 (&bfr)[8], f32x4& hacc, f32x4& gacc)
{
    #pragma unroll
    for (int ks = 0; ks < 8; ++ks) {
        float4 u = buf[2 * ks], v = buf[2 * ks + 1];
        bf16x8 a;
        a[0] = (__bf16)u.x; a[1] = (__bf16)u.y; a[2] = (__bf16)u.z; a[3] = (__bf16)u.w;
        a[4] = (__bf16)v.x; a[5] = (__bf16)v.y; a[6] = (__bf16)v.z; a[7] = (__bf16)v.w;
        hacc = __builtin_amdgcn_mfma_f32_16x16x32_bf16(a, bfr[ks], hacc, 0, 0, 0);
        gacc = __builtin_amdgcn_mfma_f32_16x16x32_bf16(a, a,       gacc, 0, 0, 0);
    }
}

static __device__ __forceinline__ void store_group(
    int nloc0, int col, int kb, const f32x4& hacc, const f32x4& gacc,
    float* logits, float* sS, float* sQ)
{
    #pragma unroll
    for (int i = 0; i < 4; ++i) {
        int n = nloc0 + (kb << 2) + i;       // C/D: col=lane&15, row=kb*4+i
        if (col < HH)       logits[col * NN + n] = hacc[i];
        else if (col == HH) sS[n] = hacc[i];
    }
    if (kb == (col >> 2)) sQ[nloc0 + col] = gacc[col & 3];   // Gram diagonal
}

__global__ __launch_bounds__(1024, 4) void k_fused(
    const float* __restrict__ msa, const float* __restrict__ Wq,
    const float* __restrict__ bq, const float* __restrict__ Wk,
    const float* __restrict__ gamma, const float* __restrict__ beta,
    float* __restrict__ out)
{
    const int l = blockIdx.x;
    const int tid = threadIdx.x, wave = tid >> 6, lane = tid & 63;
    const int col = lane & 15, kb = lane >> 4;

    __shared__ __align__(16) float logits[HH * NN];  // 16 KB
    __shared__ __align__(16) float sS[NN];           // Σx̂
    __shared__ __align__(16) float sQ[NN];           // Σx̂²
    __shared__ __align__(16) __bf16 WgL[16 * WGS];   // 8.25 KB
    __shared__ __align__(16) float qpart[4][264];    // Wq partials (padded)
    __shared__ float lnx[DD];
    __shared__ float qv[DD];
    __shared__ float red8[8];
    __shared__ float stats[16];
    __shared__ float Gs[HH];

    // ---------- Phase 1 FIRST, with a clean memory queue (no msa flood ahead of it) ----------
    {
        float x0 = (tid < DD) ? msa[(size_t)l * DD + tid] : 0.f;
        float s = x0, ss = x0 * x0;
        #pragma unroll
        for (int m = 32; m >= 1; m >>= 1) { s += __shfl_xor(s, m); ss += __shfl_xor(ss, m); }
        if (tid < DD && lane == 0) { red8[wave * 2] = s; red8[wave * 2 + 1] = ss; }
        lb_sync();
        if (tid < DD) {
            float sm = red8[0] + red8[2] + red8[4] + red8[6];
            float sq = red8[1] + red8[3] + red8[5] + red8[7];
            float mean = sm * (1.f / DD);
            float var  = sq * (1.f / DD) - mean * mean;
            float rs   = rsqrtf(var + EPSF);
            lnx[tid] = (x0 - mean) * rs * gamma[tid] + beta[tid];
        }
        lb_sync();
        // Wq GEMV: 4-way row split, 1024 tasks: r = tid&255, quarter = tid>>8
        {
            const int r = tid & 255, qtr = tid >> 8;
            const float4* wr = (const float4*)(Wq + (size_t)r * DD) + qtr * 16;
            const float* lx = lnx + qtr * 64;
            float acc = 0.f;
            #pragma unroll 4
            for (int j = 0; j < 16; ++j) {
                float4 w4 = wr[j];
                acc += lx[4*j] * w4.x + lx[4*j+1] * w4.y + lx[4*j+2] * w4.z + lx[4*j+3] * w4.w;
            }
            qpart[qtr][r] = acc;
        }
        lb_sync();
        if (tid < DD)
            qv[tid] = (qpart[0][tid] + qpart[1][tid] + qpart[2][tid] + qpart[3][tid]
                       + bq[tid]) * 0.17677669529663687f;
        lb_sync();
        // Wk GEMV: 2 heads per thread: c = tid&255, h ∈ {tid>>8, (tid>>8)+4}
        {
            const int c = tid & 255, hb = tid >> 8;
            const float gm = gamma[c];
            #pragma unroll
            for (int hi = 0; hi < 2; ++hi) {
                int h = hb + hi * 4;
                float a = 0.f;
                const float* wk = Wk + ((size_t)h * 32) * DD + c;
                #pragma unroll 8
                for (int d = 0; d < 32; ++d)
                    a += qv[h * 32 + d] * wk[(size_t)d * DD];
                WgL[h * WGS + c] = (__bf16)(gm * a);
            }
        }
        if (tid < DD) {
            WgL[8 * WGS + tid] = (__bf16)1.0f;     // ones column -> row sums
            #pragma unroll
            for (int h = 9; h < 16; ++h) WgL[h * WGS + tid] = (__bf16)0.0f;
        }
        lb_sync();
        if (wave < HH) {                           // G[h] = sum_c Wg[h][c]
            float gsum = 0.f;
            #pragma unroll
            for (int i = 0; i < 4; ++i) gsum += (float)WgL[wave * WGS + lane * 4 + i];
            #pragma unroll
            for (int m = 32; m >= 1; m >>= 1) gsum += __shfl_xor(gsum, m);
            if (lane == 0) Gs[wave] = gsum;
        }
        lb_sync();
    }

    // ---------- B fragments ----------
    bf16x8 bfr[8];
    #pragma unroll
    for (int ks = 0; ks < 8; ++ks)
        bfr[ks] = *(const bf16x8*)&WgL[col * WGS + ks * 32 + kb * 8];

    // ---------- Main: 16 waves × 2 groups of 16 rows; loads issued post-phase-1 ----------
    const f32x4 z = {0.f, 0.f, 0.f, 0.f};
    float4 A[16];
    load_group(msa, l, wave * 16, col, kb, A);
    {
        f32x4 ha = z, ga = z;
        compute_group(A, bfr, ha, ga);
        store_group(wave * 16, col, kb, ha, ga, logits, sS, sQ);
    }
    load_group(msa, l, 256 + wave * 16, col, kb, A);
    {
        f32x4 ha = z, ga = z;
        compute_group(A, bfr, ha, ga);
        store_group(256 + wave * 16, col, kb, ha, ga, logits, sS, sQ);
    }
    lb_sync();

    // ---------- softmax stats: waves 0-7 -> head h=wave over all 512 n ----------
    if (wave < HH) {
        const int h = wave;
        const float Gh = Gs[h];
        const float* lp = logits + h * NN;
        float4 ra = ((const float4*)lp)[lane * 2];
        float4 rb = ((const float4*)lp)[lane * 2 + 1];
        float4 sa = ((const float4*)sS)[lane * 2];
        float4 sb = ((const float4*)sS)[lane * 2 + 1];
        float4 qa = ((const float4*)sQ)[lane * 2];
        float4 qb = ((const float4*)sQ)[lane * 2 + 1];
        float raw[8] = {ra.x, ra.y, ra.z, ra.w, rb.x, rb.y, rb.z, rb.w};
        float sv[8]  = {sa.x, sa.y, sa.z, sa.w, sb.x, sb.y, sb.z, sb.w};
        float qv2[8] = {qa.x, qa.y, qa.z, qa.w, qb.x, qb.y, qb.z, qb.w};
        float adj[8];
        #pragma unroll
        for (int i = 0; i < 8; ++i) {
            float mean = sv[i] * (1.f / DD);
            float var  = qv2[i] * (1.f / DD) - mean * mean;
            float rs   = rsqrtf(var + EPSF);
            adj[i] = rs * (raw[i] - mean * Gh);
        }
        float mx = adj[0];
        #pragma unroll
        for (int i = 1; i < 8; ++i) mx = fmaxf(mx, adj[i]);
        #pragma unroll
        for (int m = 32; m >= 1; m >>= 1) mx = fmaxf(mx, __shfl_xor(mx, m));
        float sm = 0.f;
        #pragma unroll
        for (int i = 0; i < 8; ++i) sm += __expf(adj[i] - mx);
        #pragma unroll
        for (int m = 32; m >= 1; m >>= 1) sm += __shfl_xor(sm, m);
        if (lane == 0) { stats[wave] = mx; stats[8 + wave] = 1.f / sm; }
    }
    lb_sync();

    // ---------- epilogue: thread t<512 -> n=t, 8 heads, fp32 out ----------
    if (tid < NN) {
        const int n = tid;
        float s = sS[n], q2 = sQ[n];
        float mean = s * (1.f / DD);
        float var  = q2 * (1.f / DD) - mean * mean;
        float rs   = rsqrtf(var + EPSF);
        float o[8];
        #pragma unroll
        for (int h = 0; h < HH; ++h) {
            float adj = rs * (logits[h * NN + n] - mean * Gs[h]);
            o[h] = __expf(adj - stats[h]) * stats[8 + h];
        }
        float* op = out + (size_t)n * LL * HH + (size_t)l * HH;
        float4 p0 = {o[0], o[1], o[2], o[3]};
        float4 p1 = {o[4], o[5], o[6], o[7]};
        *(float4*)(op)     = p0;
        *(float4*)(op + 4) = p1;
    }
}

extern "C" void kernel_launch(void* const* d_in, const int* in_sizes, int n_in,
                              void* d_out, int out_size, void* d_ws, size_t ws_size,
                              hipStream_t stream) {
    (void)in_sizes; (void)n_in; (void)out_size; (void)d_ws; (void)ws_size;
    const float* msa   = (const float*)d_in[0];
    const float* Wq    = (const float*)d_in[1];
    const float* bq    = (const float*)d_in[2];
    const float* Wk    = (const float*)d_in[3];
    // d_in[4] = bk: per-(l,h) constant in logits -> cancelled by softmax over n.
    const float* gamma = (const float*)d_in[5];
    const float* beta  = (const float*)d_in[6];
    k_fused<<<dim3(LL), dim3(1024), 0, stream>>>(msa, Wq, bq, Wk, gamma, beta, (float*)d_out);
}

// Round 15
// 40.850 us; speedup vs baseline: 1.1641x; 1.0058x over previous
//
#include <hip/hip_runtime.h>
#include <hip/hip_bf16.h>
#include <cstdint>

#define LL 256   // L
#define NN 512   // N
#define DD 256   // D
#define HH 8
#define EPSF 1e-5f
#define WGS 264  // padded LDS row stride (bf16 elems) for Wg

typedef __attribute__((ext_vector_type(8))) __bf16 bf16x8;
typedef __attribute__((ext_vector_type(4))) float f32x4;

static __device__ __forceinline__ void lb_sync() {
    // barrier WITHOUT vmcnt drain: LDS-publish only; global loads stay in flight
    __builtin_amdgcn_sched_barrier(0);
    asm volatile("s_waitcnt lgkmcnt(0)" ::: "memory");
    __builtin_amdgcn_s_barrier();
    __builtin_amdgcn_sched_barrier(0);
}

static __device__ __forceinline__ void load_group(
    const float* __restrict__ msa, int l, int row0, int col, int kb, float4 (&buf)[16])
{
    const float* rp = msa + ((size_t)(row0 + col) * LL + l) * DD + (kb << 3);
    #pragma unroll
    for (int ks = 0; ks < 8; ++ks) {
        buf[2 * ks]     = *(const float4*)(rp + ks * 32);
        buf[2 * ks + 1] = *(const float4*)(rp + ks * 32 + 4);
    }
}

static __device__ __forceinline__ void compute_group(
    const float4 (&buf)[16], const bf16x8 (&bfr)[8], f32x4& hacc, f32x4& gacc)
{
    #pragma unroll
    for (int ks = 0; ks < 8; ++ks) {
        float4 u = buf[2 * ks], v = buf[2 * ks + 1];
        bf16x8 a;
        a[0] = (__bf16)u.x; a[1] = (__bf16)u.y; a[2] = (__bf16)u.z; a[3] = (__bf16)u.w;
        a[4] = (__bf16)v.x; a[5] = (__bf16)v.y; a[6] = (__bf16)v.z; a[7] = (__bf16)v.w;
        hacc = __builtin_amdgcn_mfma_f32_16x16x32_bf16(a, bfr[ks], hacc, 0, 0, 0);
        gacc = __builtin_amdgcn_mfma_f32_16x16x32_bf16(a, a,       gacc, 0, 0, 0);
    }
}

static __device__ __forceinline__ void store_group(
    int nloc0, int col, int kb, const f32x4& hacc, const f32x4& gacc,
    float* logits, float* sS, float* sQ)
{
    #pragma unroll
    for (int i = 0; i < 4; ++i) {
        int n = nloc0 + (kb << 2) + i;       // C/D: col=lane&15, row=kb*4+i
        if (col < HH)       logits[col * NN + n] = hacc[i];
        else if (col == HH) sS[n] = hacc[i];
    }
    if (kb == (col >> 2)) sQ[nloc0 + col] = gacc[col & 3];   // Gram diagonal
}

__global__ __launch_bounds__(1024, 4) void k_fused(
    const float* __restrict__ msa, const float* __restrict__ Wq,
    const float* __restrict__ bq, const float* __restrict__ Wk,
    const float* __restrict__ gamma, const float* __restrict__ beta,
    float* __restrict__ out)
{
    const int l = blockIdx.x;
    const int tid = threadIdx.x, wave = tid >> 6, lane = tid & 63;
    const int col = lane & 15, kb = lane >> 4;

    __shared__ __align__(16) float logits[HH * NN];  // 16 KB (raw dots, then adj in-place)
    __shared__ __align__(16) float sS[NN];           // Σx̂
    __shared__ __align__(16) float sQ[NN];           // Σx̂²
    __shared__ __align__(16) __bf16 WgL[16 * WGS];   // 8.25 KB
    __shared__ __align__(16) float qpart[4][264];    // Wq partials (padded)
    __shared__ float lnx[DD];
    __shared__ float qv[DD];
    __shared__ float red8[8];
    __shared__ float Gpart[HH][4];
    __shared__ float redM[HH][2];
    __shared__ float redS[HH][2];
    __shared__ float stats[16];
    __shared__ float Gs[HH];

    // ---------- Phase 1: Wg = gamma ⊙ (q·Wk) in LDS (5 barriers, fused Gs) ----------
    {
        float x0 = (tid < DD) ? msa[(size_t)l * DD + tid] : 0.f;
        float s = x0, ss = x0 * x0;
        #pragma unroll
        for (int m = 32; m >= 1; m >>= 1) { s += __shfl_xor(s, m); ss += __shfl_xor(ss, m); }
        if (tid < DD && lane == 0) { red8[wave * 2] = s; red8[wave * 2 + 1] = ss; }
        lb_sync();
        if (tid < DD) {
            float sm = red8[0] + red8[2] + red8[4] + red8[6];
            float sq = red8[1] + red8[3] + red8[5] + red8[7];
            float mean = sm * (1.f / DD);
            float var  = sq * (1.f / DD) - mean * mean;
            float rs   = rsqrtf(var + EPSF);
            lnx[tid] = (x0 - mean) * rs * gamma[tid] + beta[tid];
        }
        lb_sync();
        // Wq GEMV: 4-way row split, 1024 tasks: r = tid&255, quarter = tid>>8
        {
            const int r = tid & 255, qtr = tid >> 8;
            const float4* wr = (const float4*)(Wq + (size_t)r * DD) + qtr * 16;
            const float* lx = lnx + qtr * 64;
            float acc = 0.f;
            #pragma unroll 4
            for (int j = 0; j < 16; ++j) {
                float4 w4 = wr[j];
                acc += lx[4*j] * w4.x + lx[4*j+1] * w4.y + lx[4*j+2] * w4.z + lx[4*j+3] * w4.w;
            }
            qpart[qtr][r] = acc;
        }
        lb_sync();
        if (tid < DD)
            qv[tid] = (qpart[0][tid] + qpart[1][tid] + qpart[2][tid] + qpart[3][tid]
                       + bq[tid]) * 0.17677669529663687f;
        lb_sync();
        // Wk GEMV + fused Gs: c = tid&255, hb = tid>>8; heads hb, hb+4.
        // Wave wv covers c-range (wv&3)*64..+63 for head-base wv>>2.
        {
            const int c = tid & 255, hb = tid >> 8;
            const float gm = gamma[c];
            float gp[2];
            #pragma unroll
            for (int hi = 0; hi < 2; ++hi) {
                int h = hb + hi * 4;
                float a = 0.f;
                const float* wk = Wk + ((size_t)h * 32) * DD + c;
                #pragma unroll 8
                for (int d = 0; d < 32; ++d)
                    a += qv[h * 32 + d] * wk[(size_t)d * DD];
                __bf16 w = (__bf16)(gm * a);
                WgL[h * WGS + c] = w;
                float wf = (float)w;                       // post-rounding value
                #pragma unroll
                for (int m = 32; m >= 1; m >>= 1) wf += __shfl_xor(wf, m);
                gp[hi] = wf;
            }
            if (lane == 0) {
                Gpart[hb][wave & 3]     = gp[0];
                Gpart[hb + 4][wave & 3] = gp[1];
            }
        }
        if (tid < DD) {
            WgL[8 * WGS + tid] = (__bf16)1.0f;     // ones column -> row sums
            #pragma unroll
            for (int h = 9; h < 16; ++h) WgL[h * WGS + tid] = (__bf16)0.0f;
        }
        lb_sync();
        if (tid < HH)
            Gs[tid] = Gpart[tid][0] + Gpart[tid][1] + Gpart[tid][2] + Gpart[tid][3];
        // Gs visibility for stats is covered by the main-loop barrier.
    }

    // ---------- B fragments ----------
    bf16x8 bfr[8];
    #pragma unroll
    for (int ks = 0; ks < 8; ++ks)
        bfr[ks] = *(const bf16x8*)&WgL[col * WGS + ks * 32 + kb * 8];

    // ---------- Main: 16 waves × 2 groups of 16 rows ----------
    const f32x4 z = {0.f, 0.f, 0.f, 0.f};
    float4 A[16];
    load_group(msa, l, wave * 16, col, kb, A);
    {
        f32x4 ha = z, ga = z;
        compute_group(A, bfr, ha, ga);
        store_group(wave * 16, col, kb, ha, ga, logits, sS, sQ);
    }
    load_group(msa, l, 256 + wave * 16, col, kb, A);
    {
        f32x4 ha = z, ga = z;
        compute_group(A, bfr, ha, ga);
        store_group(256 + wave * 16, col, kb, ha, ga, logits, sS, sQ);
    }
    lb_sync();

    // ---------- softmax stats: 16 waves -> (head = wave&7, n-half = wave>>3) ----------
    {
        const int h = wave & 7, hf2 = wave >> 3;
        const float Gh = Gs[h];
        float* lp = logits + h * NN + hf2 * 256;
        float4 ra = ((const float4*)lp)[lane];
        float4 sa = ((const float4*)(sS + hf2 * 256))[lane];
        float4 qa = ((const float4*)(sQ + hf2 * 256))[lane];
        float adj[4];
        #pragma unroll
        for (int i = 0; i < 4; ++i) {
            float mean = sa[i] * (1.f / DD);
            float var  = qa[i] * (1.f / DD) - mean * mean;
            float rs   = rsqrtf(var + EPSF);
            adj[i] = rs * (ra[i] - mean * Gh);
        }
        float4 w4 = {adj[0], adj[1], adj[2], adj[3]};
        ((float4*)lp)[lane] = w4;                       // adj in place
        float mx = fmaxf(fmaxf(adj[0], adj[1]), fmaxf(adj[2], adj[3]));
        #pragma unroll
        for (int m = 32; m >= 1; m >>= 1) mx = fmaxf(mx, __shfl_xor(mx, m));
        float sm = 0.f;
        #pragma unroll
        for (int i = 0; i < 4; ++i) sm += __expf(adj[i] - mx);
        #pragma unroll
        for (int m = 32; m >= 1; m >>= 1) sm += __shfl_xor(sm, m);
        if (lane == 0) { redM[h][hf2] = mx; redS[h][hf2] = sm; }
    }
    lb_sync();
    if (tid < HH) {
        float m0 = redM[tid][0], m1 = redM[tid][1];
        float m = fmaxf(m0, m1);
        float s = redS[tid][0] * __expf(m0 - m) + redS[tid][1] * __expf(m1 - m);
        stats[tid] = m; stats[8 + tid] = 1.f / s;
    }
    lb_sync();

    // ---------- epilogue: thread t<512 -> n=t, 8 heads (adj precomputed) ----------
    if (tid < NN) {
        const int n = tid;
        float o[8];
        #pragma unroll
        for (int h = 0; h < HH; ++h)
            o[h] = __expf(logits[h * NN + n] - stats[h]) * stats[8 + h];
        float* op = out + (size_t)n * LL * HH + (size_t)l * HH;
        float4 p0 = {o[0], o[1], o[2], o[3]};
        float4 p1 = {o[4], o[5], o[6], o[7]};
        *(float4*)(op)     = p0;
        *(float4*)(op + 4) = p1;
    }
}

extern "C" void kernel_launch(void* const* d_in, const int* in_sizes, int n_in,
                              void* d_out, int out_size, void* d_ws, size_t ws_size,
                              hipStream_t stream) {
    (void)in_sizes; (void)n_in; (void)out_size; (void)d_ws; (void)ws_size;
    const float* msa   = (const float*)d_in[0];
    const float* Wq    = (const float*)d_in[1];
    const float* bq    = (const float*)d_in[2];
    const float* Wk    = (const float*)d_in[3];
    // d_in[4] = bk: per-(l,h) constant in logits -> cancelled by softmax over n.
    const float* gamma = (const float*)d_in[5];
    const float* beta  = (const float*)d_in[6];
    k_fused<<<dim3(LL), dim3(1024), 0, stream>>>(msa, Wq, bq, Wk, gamma, beta, (float*)d_out);
}